// Round 17
// baseline (437.252 us; speedup 1.0000x reference)
//
#include <hip/hip_runtime.h>
#include <hip/hip_bf16.h>
#include <math.h>

#define TPB 256

typedef __attribute__((ext_vector_type(8))) _Float16 hfrag8;
typedef __attribute__((ext_vector_type(2))) _Float16 h2;
typedef __attribute__((ext_vector_type(4))) float f32x4;

union HU { unsigned int u; h2 h; };
union US8 { unsigned short us[8]; uint4 v; };

static __device__ __forceinline__ h2 as_h2(unsigned int u) { HU c; c.u = u; return c.h; }
static __device__ __forceinline__ unsigned short f2h_bits(float f) {
  union { _Float16 h; unsigned short s; } c; c.h = (_Float16)f; return c.s;
}

// DPP row-rotate ring reduction within each 16-lane row.
#define DPP_ROR(v, C) __int_as_float(__builtin_amdgcn_update_dpp( \
    __float_as_int(v), __float_as_int(v), (C), 0xf, 0xf, false))
static __device__ __forceinline__ float red16(float p) {
  p += DPP_ROR(p, 0x121);  // row_ror:1
  p += DPP_ROR(p, 0x122);  // row_ror:2
  p += DPP_ROR(p, 0x124);  // row_ror:4
  p += DPP_ROR(p, 0x128);  // row_ror:8
  return p;
}

// ---------------- degrees + W->f16 transpose (fused) ----------------
__global__ void k_deg_wprep(const int* __restrict__ ei, int E, int ET, int* __restrict__ deg,
                            const float* __restrict__ Wl1, const float* __restrict__ Wr1,
                            const float* __restrict__ Wl2, const float* __restrict__ Wr2,
                            unsigned short* __restrict__ wt1l, unsigned short* __restrict__ wt1r,
                            unsigned short* __restrict__ wt2l, unsigned short* __restrict__ wt2r,
                            int egrid) {
  int b = blockIdx.x;
  if (b < egrid) {
    int e = b * TPB + threadIdx.x;
    if (e < ET) {
      int dst = (e < E) ? ei[E + e] : (e - E);
      atomicAdd(&deg[dst], 1);
    }
    return;
  }
  int i = (b - egrid) * TPB + threadIdx.x;
  if (i < 32768) {
    int c = i >> 7, k = i & 127;
    wt1l[i] = f2h_bits(Wl1[(size_t)k * 256 + c]);
  } else if (i < 65536) {
    int j = i - 32768; int c = j >> 7, k = j & 127;
    wt1r[j] = f2h_bits(Wr1[(size_t)k * 256 + c]);
  } else if (i < 69632) {
    int j = i - 65536; int c = j >> 6, k = j & 63;
    wt2l[j] = f2h_bits(Wl2[(size_t)k * 64 + c]);
  } else if (i < 73728) {
    int j = i - 69632; int c = j >> 6, k = j & 63;
    wt2r[j] = f2h_bits(Wr2[(size_t)k * 64 + c]);
  }
}

// ---------------- one-dispatch padded-degree scan ----------------
__global__ void k_scanf(const int* __restrict__ deg, int N,
                        int* __restrict__ rowoff, int* __restrict__ cursor) {
  __shared__ int sm[TPB];
  int t = threadIdx.x;
  int pref = blockIdx.x * TPB;
  int acc = 0;
  for (int j = t; j < pref; j += TPB) acc += (deg[j] + 3) & ~3;
  sm[t] = acc;
  __syncthreads();
  for (int d = TPB / 2; d > 0; d >>= 1) {
    if (t < d) sm[t] += sm[t + d];
    __syncthreads();
  }
  int base = sm[0];
  __syncthreads();
  int i = pref + t;
  int v = (i < N) ? ((deg[i] + 3) & ~3) : 0;
  sm[t] = v;
  __syncthreads();
  for (int d = 1; d < TPB; d <<= 1) {
    int tmp = (t >= d) ? sm[t - d] : 0;
    __syncthreads();
    sm[t] += tmp;
    __syncthreads();
  }
  if (i < N) {
    int off = base + sm[t] - v;  // exclusive, 4-aligned
    rowoff[i] = off;
    cursor[i] = off;
  }
}

// fill + zero per-row padding slots (extra threads beyond ET)
__global__ void k_fill(const int* __restrict__ ei, int E, int ET, int N,
                       const int* __restrict__ rowoff, const int* __restrict__ deg,
                       int* __restrict__ cursor, int* __restrict__ csrc) {
  int e = blockIdx.x * blockDim.x + threadIdx.x;
  if (e < ET) {
    int src, dst;
    if (e < E) { src = ei[e]; dst = ei[E + e]; } else { src = dst = e - E; }
    csrc[atomicAdd(&cursor[dst], 1)] = src;
  } else {
    int i = e - ET;
    if (i < N) {
      int dg = deg[i];
      int beg = rowoff[i] + dg;
      int end = rowoff[i] + ((dg + 3) & ~3);
      for (int k = beg; k < end; ++k) csrc[k] = 0;
    }
  }
}

// ---------------- MFMA GEMM, 64-row tiles: out{0,1}_f16 = act(A) @ Wt{0,1}^T + b ----------
__global__ void k_gemm_mfma(const void* __restrict__ Avoid, int af16,
                            const float* __restrict__ affine,
                            const unsigned short* __restrict__ Wt0, const float* __restrict__ b0,
                            const unsigned short* __restrict__ Wt1, const float* __restrict__ b1,
                            unsigned short* __restrict__ out0, unsigned short* __restrict__ out1,
                            int M, int K, int Nc, int mtile, int nt4) {
  extern __shared__ short lds[];
  short* As = lds;
  short* Bls = lds + 64 * K;
  short* Brs = lds + 128 * K;
  int m, nt;
  if (nt4) {
    int xcd = blockIdx.x & 7, gg = blockIdx.x >> 3;
    nt = gg & 3; m = ((gg >> 2) << 3) | xcd;
    if (m >= mtile) return;
  } else {
    m = blockIdx.x; nt = 0;
  }
  const int r0 = m * 64, n0 = nt * 64;
  const int tid = threadIdx.x;
  const int Kb = K * 2;

  if (af16) {
    const unsigned short* A16 = (const unsigned short*)Avoid;
    const int cpr8 = K >> 3;
    for (int idx = tid; idx < 64 * cpr8; idx += TPB) {
      int row = idx / cpr8, k8 = (idx - row * cpr8) * 8;
      int gr = r0 + row;
      uint4 av = make_uint4(0, 0, 0, 0);
      if (gr < M) av = *(const uint4*)(A16 + (size_t)gr * K + k8);
      unsigned int wds[4] = {av.x, av.y, av.z, av.w};
      US8 res;
#pragma unroll
      for (int j = 0; j < 4; ++j) {
        h2 hv = as_h2(wds[j]);
        int c = k8 + j * 2;
        float f0 = fmaxf((float)hv.x * affine[c] + affine[64 + c], 0.f);
        float f1 = fmaxf((float)hv.y * affine[c + 1] + affine[64 + c + 1], 0.f);
        res.us[j * 2] = f2h_bits(f0);
        res.us[j * 2 + 1] = f2h_bits(f1);
      }
      int kb = (k8 * 2) ^ ((row & 7) << 4);
      *(uint4*)((char*)As + row * Kb + kb) = res.v;
    }
  } else {
    const float* A = (const float*)Avoid;
    const int fpr = K >> 2;
    for (int idx = tid; idx < 64 * fpr; idx += TPB) {
      int row = idx / fpr, c4 = idx - row * fpr;
      int gr = r0 + row;
      float4 v = make_float4(0.f, 0.f, 0.f, 0.f);
      if (gr < M) v = *(const float4*)(A + (size_t)gr * K + c4 * 4);
      ushort4 pk;
      pk.x = f2h_bits(v.x); pk.y = f2h_bits(v.y); pk.z = f2h_bits(v.z); pk.w = f2h_bits(v.w);
      int kb = (c4 * 8) ^ ((row & 7) << 4);
      *(ushort4*)((char*)As + row * Kb + kb) = pk;
    }
  }
  const int cpr = K >> 3;
  for (int idx = tid; idx < 64 * cpr; idx += TPB) {
    int c = idx / cpr, k8 = (idx - c * cpr) * 8;
    int kb = (k8 * 2) ^ ((c & 7) << 4);
    uint4 w0 = *(const uint4*)(Wt0 + (size_t)(n0 + c) * K + k8);
    *(uint4*)((char*)Bls + c * Kb + kb) = w0;
    uint4 w1 = *(const uint4*)(Wt1 + (size_t)(n0 + c) * K + k8);
    *(uint4*)((char*)Brs + c * Kb + kb) = w1;
  }
  __syncthreads();

  const int w = tid >> 6, lane = tid & 63;
  const int arow = w * 16 + (lane & 15);
  const int l16 = (lane >> 4) << 3;
  f32x4 accL[4], accR[4];
#pragma unroll
  for (int i = 0; i < 4; ++i) { accL[i] = (f32x4)0.f; accR[i] = (f32x4)0.f; }
  for (int k0 = 0; k0 < K; k0 += 32) {
    int kb = (k0 + l16) * 2;
    hfrag8 af = *(hfrag8*)((char*)As + arow * Kb + (kb ^ ((arow & 7) << 4)));
#pragma unroll
    for (int cf = 0; cf < 4; ++cf) {
      int col = cf * 16 + (lane & 15);
      int cb = col * Kb + (kb ^ ((col & 7) << 4));
      hfrag8 bl = *(hfrag8*)((char*)Bls + cb);
      accL[cf] = __builtin_amdgcn_mfma_f32_16x16x32_f16(af, bl, accL[cf], 0, 0, 0);
      hfrag8 br = *(hfrag8*)((char*)Brs + cb);
      accR[cf] = __builtin_amdgcn_mfma_f32_16x16x32_f16(af, br, accR[cf], 0, 0, 0);
    }
  }
  const int rbase = r0 + w * 16 + ((lane >> 4) << 2);
  const int cbase = n0 + (lane & 15);
#pragma unroll
  for (int cf = 0; cf < 4; ++cf) {
    int gcol = cbase + cf * 16;
    float bb0 = b0[gcol], bb1 = b1[gcol];
#pragma unroll
    for (int r = 0; r < 4; ++r) {
      int grow = rbase + r;
      if (grow < M) {
        out0[(size_t)grow * Nc + gcol] = f2h_bits(accL[cf][r] + bb0);
        out1[(size_t)grow * Nc + gcol] = f2h_bits(accR[cf][r] + bb1);
      }
    }
  }
}

// ---------------- GATv2 layer 1: H=4, C=64; one node/wave; f16 math; f16 out ----------------
__global__ __launch_bounds__(TPB) void k_gat1(
    const unsigned short* __restrict__ xl, const unsigned short* __restrict__ xr,
    const int* __restrict__ rowoff, const int* __restrict__ deg,
    const int* __restrict__ csrc,
    const float* __restrict__ att, const float* __restrict__ bias,
    unsigned short* __restrict__ out, int N) {
  int node = (blockIdx.x * TPB + threadIdx.x) >> 6;
  int lane = threadIdx.x & 63;
  if (node >= N) return;
  int l4 = lane * 4;
  float4 atv = *(const float4*)(att + l4);
  h2 at01, at23;
  at01.x = (_Float16)atv.x; at01.y = (_Float16)atv.y;
  at23.x = (_Float16)atv.z; at23.y = (_Float16)atv.w;
  float4 bb = *(const float4*)(bias + l4);
  uint2 rv = *(const uint2*)(xr + (node << 8) + l4);
  h2 xr01 = as_h2(rv.x), xr23 = as_h2(rv.y);
  const _Float16 c02 = (_Float16)0.2f;
  int beg = rowoff[node];
  int dg = deg[node];
  int endR = beg + dg;          // real end
  int endF = beg + (dg & ~3);   // full quads
  float s = 0.f, a0 = 0.f, a1 = 0.f, a2 = 0.f, a3 = 0.f;
  int k = beg;
  for (; k < endF; k += 4) {
    int4 q = *(const int4*)(csrc + k);  // 4-aligned (padded rows)
    uint2 vv[4];
    vv[0] = *(const uint2*)(xl + (q.x << 8) + l4);
    vv[1] = *(const uint2*)(xl + (q.y << 8) + l4);
    vv[2] = *(const uint2*)(xl + (q.z << 8) + l4);
    vv[3] = *(const uint2*)(xl + (q.w << 8) + l4);
    float ps[4];
#pragma unroll
    for (int u = 0; u < 4; ++u) {
      h2 x01 = as_h2(vv[u].x), x23 = as_h2(vv[u].y);
      h2 t01 = x01 + xr01, t23 = x23 + xr23;
      h2 l01 = __builtin_elementwise_max(t01, t01 * c02);
      h2 l23 = __builtin_elementwise_max(t23, t23 * c02);
      ps[u] = __builtin_amdgcn_fdot2(l01, at01,
              __builtin_amdgcn_fdot2(l23, at23, 0.f, false), false);
    }
#pragma unroll
    for (int u = 0; u < 4; ++u) ps[u] = red16(ps[u]);
#pragma unroll
    for (int u = 0; u < 4; ++u) {
      float wv = __expf(ps[u]);
      h2 x01 = as_h2(vv[u].x), x23 = as_h2(vv[u].y);
      s += wv;
      a0 += wv * (float)x01.x; a1 += wv * (float)x01.y;
      a2 += wv * (float)x23.x; a3 += wv * (float)x23.y;
    }
  }
  if (k < endR) {  // one predicated aligned quad (padding srcs are 0 -> valid row)
    int4 q = *(const int4*)(csrc + k);
    uint2 vv[4];
    vv[0] = *(const uint2*)(xl + (q.x << 8) + l4);
    vv[1] = *(const uint2*)(xl + (q.y << 8) + l4);
    vv[2] = *(const uint2*)(xl + (q.z << 8) + l4);
    vv[3] = *(const uint2*)(xl + (q.w << 8) + l4);
    float ps[4];
#pragma unroll
    for (int u = 0; u < 4; ++u) {
      h2 x01 = as_h2(vv[u].x), x23 = as_h2(vv[u].y);
      h2 t01 = x01 + xr01, t23 = x23 + xr23;
      h2 l01 = __builtin_elementwise_max(t01, t01 * c02);
      h2 l23 = __builtin_elementwise_max(t23, t23 * c02);
      ps[u] = __builtin_amdgcn_fdot2(l01, at01,
              __builtin_amdgcn_fdot2(l23, at23, 0.f, false), false);
    }
#pragma unroll
    for (int u = 0; u < 4; ++u) ps[u] = red16(ps[u]);
#pragma unroll
    for (int u = 0; u < 4; ++u) {
      float wv = (k + u < endR) ? __expf(ps[u]) : 0.f;
      h2 x01 = as_h2(vv[u].x), x23 = as_h2(vv[u].y);
      s += wv;
      a0 += wv * (float)x01.x; a1 += wv * (float)x01.y;
      a2 += wv * (float)x23.x; a3 += wv * (float)x23.y;
    }
  }
  float inv = 1.f / (s + 1e-16f);
  a0 *= inv; a1 *= inv; a2 *= inv; a3 *= inv;
  a0 += __shfl_xor(a0, 16); a0 += __shfl_xor(a0, 32);
  a1 += __shfl_xor(a1, 16); a1 += __shfl_xor(a1, 32);
  a2 += __shfl_xor(a2, 16); a2 += __shfl_xor(a2, 32);
  a3 += __shfl_xor(a3, 16); a3 += __shfl_xor(a3, 32);
  if (lane < 16) {
    ushort4 o;
    o.x = f2h_bits(a0 * 0.25f + bb.x);
    o.y = f2h_bits(a1 * 0.25f + bb.y);
    o.z = f2h_bits(a2 * 0.25f + bb.z);
    o.w = f2h_bits(a3 * 0.25f + bb.w);
    *(ushort4*)(out + (node << 6) + l4) = o;
  }
}

// ---------------- GATv2 layer 2: H=1, C=64; 4 edges/wave; f16 math; f32 out ----------------
__global__ __launch_bounds__(TPB) void k_gat2(
    const unsigned short* __restrict__ xl, const unsigned short* __restrict__ xr,
    const int* __restrict__ rowoff, const int* __restrict__ deg,
    const int* __restrict__ csrc,
    const float* __restrict__ att, const float* __restrict__ bias,
    float* __restrict__ out, int N) {
  int node = (blockIdx.x * TPB + threadIdx.x) >> 6;
  int lane = threadIdx.x & 63;
  if (node >= N) return;
  int grp = lane >> 4, c4 = (lane & 15) * 4;
  float4 atv = *(const float4*)(att + c4);
  h2 at01, at23;
  at01.x = (_Float16)atv.x; at01.y = (_Float16)atv.y;
  at23.x = (_Float16)atv.z; at23.y = (_Float16)atv.w;
  float4 bb = *(const float4*)(bias + c4);
  uint2 rv = *(const uint2*)(xr + (node << 6) + c4);
  h2 xr01 = as_h2(rv.x), xr23 = as_h2(rv.y);
  const _Float16 c02 = (_Float16)0.2f;
  int beg = rowoff[node];
  int dg = deg[node];
  int endR = beg + dg;
  int quads = (dg + 3) >> 2;
  float s = 0.f, a0 = 0.f, a1 = 0.f, a2 = 0.f, a3 = 0.f;
  for (int it = 0; it < quads; ++it) {
    int kk = beg + it * 4 + grp;
    int src = csrc[kk];
    bool ok = kk < endR;
    uint2 v = *(const uint2*)(xl + (src << 6) + c4);
    h2 x01 = as_h2(v.x), x23 = as_h2(v.y);
    h2 t01 = x01 + xr01, t23 = x23 + xr23;
    h2 l01 = __builtin_elementwise_max(t01, t01 * c02);
    h2 l23 = __builtin_elementwise_max(t23, t23 * c02);
    float p = __builtin_amdgcn_fdot2(l01, at01,
              __builtin_amdgcn_fdot2(l23, at23, 0.f, false), false);
    p = red16(p);
    float wv = ok ? __expf(p) : 0.f;
    s += wv;
    a0 += wv * (float)x01.x; a1 += wv * (float)x01.y;
    a2 += wv * (float)x23.x; a3 += wv * (float)x23.y;
  }
  s += __shfl_xor(s, 16); s += __shfl_xor(s, 32);
  a0 += __shfl_xor(a0, 16); a0 += __shfl_xor(a0, 32);
  a1 += __shfl_xor(a1, 16); a1 += __shfl_xor(a1, 32);
  a2 += __shfl_xor(a2, 16); a2 += __shfl_xor(a2, 32);
  a3 += __shfl_xor(a3, 16); a3 += __shfl_xor(a3, 32);
  if (lane < 16) {
    float inv = 1.f / (s + 1e-16f);
    float4 o;
    o.x = a0 * inv + bb.x;
    o.y = a1 * inv + bb.y;
    o.z = a2 * inv + bb.z;
    o.w = a3 * inv + bb.w;
    *(float4*)(out + (node << 6) + c4) = o;
  }
}

// ---------------- BN1: stats + last-block PARALLEL finalize (f16 input) ----------------
__global__ void k_bnstatfin(const unsigned short* __restrict__ inh_, int N,
                            float* __restrict__ part, int* __restrict__ counter,
                            const float* __restrict__ g, const float* __restrict__ beta,
                            float* __restrict__ ab) {
  __shared__ float sm[TPB], sq[TPB];
  __shared__ float fin[TPB];
  __shared__ int lastsm;
  const _Float16* inh = (const _Float16*)inh_;
  int col = threadIdx.x & 63;
  int rq = threadIdx.x >> 6;
  float s0 = 0.f, q0 = 0.f, s1 = 0.f, q1 = 0.f;
  int stride = gridDim.x * 4;
  int r = blockIdx.x * 4 + rq;
  for (; r + stride < N; r += 2 * stride) {
    float v0 = (float)inh[(size_t)r * 64 + col];
    float v1 = (float)inh[(size_t)(r + stride) * 64 + col];
    s0 += v0; q0 += v0 * v0;
    s1 += v1; q1 += v1 * v1;
  }
  if (r < N) {
    float v0 = (float)inh[(size_t)r * 64 + col];
    s0 += v0; q0 += v0 * v0;
  }
  sm[threadIdx.x] = s0 + s1; sq[threadIdx.x] = q0 + q1;
  __syncthreads();
  if (threadIdx.x < 128) {
    float v;
    if (threadIdx.x < 64) {
      v = sm[threadIdx.x] + sm[threadIdx.x + 64] + sm[threadIdx.x + 128] + sm[threadIdx.x + 192];
    } else {
      int c = threadIdx.x - 64;
      v = sq[c] + sq[c + 64] + sq[c + 128] + sq[c + 192];
    }
    part[(size_t)blockIdx.x * 128 + threadIdx.x] = v;
  }
  __threadfence();
  __syncthreads();
  if (threadIdx.x == 0) lastsm = atomicAdd(counter, 1);
  __syncthreads();
  if (lastsm != gridDim.x - 1) return;
  __threadfence();
  int t = threadIdx.x;
  int c = t & 127, gidx = t >> 7;
  int B = gridDim.x;
  float acc0 = 0.f, acc1 = 0.f, acc2 = 0.f, acc3 = 0.f;
  int b = gidx;
  for (; b + 6 < B; b += 8) {
    acc0 += part[(size_t)b * 128 + c];
    acc1 += part[(size_t)(b + 2) * 128 + c];
    acc2 += part[(size_t)(b + 4) * 128 + c];
    acc3 += part[(size_t)(b + 6) * 128 + c];
  }
  for (; b < B; b += 2) acc0 += part[(size_t)b * 128 + c];
  fin[t] = (acc0 + acc1) + (acc2 + acc3);
  __syncthreads();
  if (t < 64) {
    float ts = fin[t] + fin[t + 128];
    float tq = fin[t + 64] + fin[t + 192];
    float mean = ts / (float)N;
    float var = tq / (float)N - mean * mean;
    float a = g[t] * rsqrtf(var + 1e-5f);
    ab[t] = a;
    ab[64 + t] = beta[t] - mean * a;
  }
}

// ---------------- BN2 fused: stats + finalize + spin-barrier + apply (in-place) ----------
// Grid MUST be <= 256 blocks (1 block/CU -> all co-resident; spin is deadlock-safe).
__global__ __launch_bounds__(TPB) void k_bn2fused(
    float* __restrict__ inout, int N, float* __restrict__ part,
    int* __restrict__ counter, int* __restrict__ flag,
    const float* __restrict__ g, const float* __restrict__ beta,
    float* __restrict__ ab) {
  __shared__ float sm[TPB], sq[TPB];
  __shared__ float fin[TPB];
  __shared__ int lastsm;
  int col = threadIdx.x & 63;
  int rq = threadIdx.x >> 6;
  float s0 = 0.f, q0 = 0.f, s1 = 0.f, q1 = 0.f;
  int stride = gridDim.x * 4;
  int r0 = blockIdx.x * 4 + rq;
  for (int r = r0; r < N; r += 2 * stride) {
    float v0 = inout[(size_t)r * 64 + col];
    s0 += v0; q0 += v0 * v0;
    int r2 = r + stride;
    if (r2 < N) {
      float v1 = inout[(size_t)r2 * 64 + col];
      s1 += v1; q1 += v1 * v1;
    }
  }
  sm[threadIdx.x] = s0 + s1; sq[threadIdx.x] = q0 + q1;
  __syncthreads();
  if (threadIdx.x < 128) {
    float v;
    if (threadIdx.x < 64) {
      v = sm[threadIdx.x] + sm[threadIdx.x + 64] + sm[threadIdx.x + 128] + sm[threadIdx.x + 192];
    } else {
      int c = threadIdx.x - 64;
      v = sq[c] + sq[c + 64] + sq[c + 128] + sq[c + 192];
    }
    part[(size_t)blockIdx.x * 128 + threadIdx.x] = v;
  }
  __threadfence();
  __syncthreads();
  if (threadIdx.x == 0) lastsm = atomicAdd(counter, 1);
  __syncthreads();
  if (lastsm == gridDim.x - 1) {
    // last block: parallel deterministic finalize, then release the flag
    __threadfence();
    int t = threadIdx.x;
    int c = t & 127, gidx = t >> 7;
    int B = gridDim.x;
    float acc0 = 0.f, acc1 = 0.f, acc2 = 0.f, acc3 = 0.f;
    int b = gidx;
    for (; b + 6 < B; b += 8) {
      acc0 += part[(size_t)b * 128 + c];
      acc1 += part[(size_t)(b + 2) * 128 + c];
      acc2 += part[(size_t)(b + 4) * 128 + c];
      acc3 += part[(size_t)(b + 6) * 128 + c];
    }
    for (; b < B; b += 2) acc0 += part[(size_t)b * 128 + c];
    fin[t] = (acc0 + acc1) + (acc2 + acc3);
    __syncthreads();
    if (t < 64) {
      float ts = fin[t] + fin[t + 128];
      float tq = fin[t + 64] + fin[t + 192];
      float mean = ts / (float)N;
      float var = tq / (float)N - mean * mean;
      float a = g[t] * rsqrtf(var + 1e-5f);
      ab[t] = a;
      ab[64 + t] = beta[t] - mean * a;
    }
    __syncthreads();
    __threadfence();
    if (t == 0) __hip_atomic_store(flag, 1, __ATOMIC_RELEASE, __HIP_MEMORY_SCOPE_AGENT);
  } else {
    // other blocks: spin until ab2 published
    if (threadIdx.x == 0) {
      while (__hip_atomic_load(flag, __ATOMIC_ACQUIRE, __HIP_MEMORY_SCOPE_AGENT) == 0)
        __builtin_amdgcn_s_sleep(8);
    }
    __syncthreads();
  }
  // apply in-place: per-thread fixed column -> cache scale/shift in registers
  float ac = ab[col], bc = ab[64 + col];
  for (int r = r0; r < N; r += stride) {
    size_t idx = (size_t)r * 64 + col;
    inout[idx] = fmaxf(inout[idx] * ac + bc, 0.f);
  }
}

extern "C" void kernel_launch(void* const* d_in, const int* in_sizes, int n_in,
                              void* d_out, int out_size, void* d_ws, size_t ws_size,
                              hipStream_t stream) {
  const float* x     = (const float*)d_in[0];
  const int*   ei    = (const int*)d_in[1];
  const float* Wl1   = (const float*)d_in[2];
  const float* bl1   = (const float*)d_in[3];
  const float* Wr1   = (const float*)d_in[4];
  const float* br1   = (const float*)d_in[5];
  const float* att1  = (const float*)d_in[6];
  const float* bias1 = (const float*)d_in[7];
  const float* g1    = (const float*)d_in[8];
  const float* be1   = (const float*)d_in[9];
  const float* Wl2   = (const float*)d_in[10];
  const float* bl2   = (const float*)d_in[11];
  const float* Wr2   = (const float*)d_in[12];
  const float* br2   = (const float*)d_in[13];
  const float* att2  = (const float*)d_in[14];
  const float* bias2 = (const float*)d_in[15];
  const float* g2    = (const float*)d_in[16];
  const float* be2   = (const float*)d_in[17];
  float* out = (float*)d_out;

  const int N  = in_sizes[0] / 128;   // 50000
  const int E  = in_sizes[1] / 2;     // 800000
  const int ET = E + N;
  const int ETP = ET + 4 * ((N + 255) & ~255);  // padded-CSR upper bound
  const int SB = (N + TPB - 1) / TPB; // 196

  char* p = (char*)d_ws;
  auto take = [&](size_t b) { char* q = p; p += (b + 255) & ~(size_t)255; return q; };

  unsigned short* xl1 = (unsigned short*)take((size_t)N * 256 * 2);
  unsigned short* xr1 = (unsigned short*)take((size_t)N * 256 * 2);
  unsigned short* xl2 = (unsigned short*)take((size_t)N * 64 * 2);
  unsigned short* xr2 = (unsigned short*)take((size_t)N * 64 * 2);
  unsigned short* out1 = (unsigned short*)take((size_t)N * 64 * 2);  // f16
  unsigned short* wt1l = (unsigned short*)take(256 * 128 * 2);
  unsigned short* wt1r = (unsigned short*)take(256 * 128 * 2);
  unsigned short* wt2l = (unsigned short*)take(64 * 64 * 2);
  unsigned short* wt2r = (unsigned short*)take(64 * 64 * 2);
  // zeroed span: deg + counters/flag (csrc pads zeroed in k_fill)
  int* deg    = (int*)take((size_t)N * 4);
  int* ctr    = (int*)take(1024);     // ctr[0]=bn1 cnt, ctr[64]=bn2 cnt, ctr[128]=bn2 flag
  size_t zero_bytes = (char*)ctr + 1024 - (char*)deg;
  int* csrc   = (int*)take((size_t)ETP * 4 + 16);
  int* rowoff = (int*)take((size_t)(N + 1) * 4);
  int* cursor = (int*)take((size_t)N * 4);
  float* part = (float*)take((size_t)256 * 128 * 4);
  float* ab1  = (float*)take(128 * 4);
  float* ab2  = (float*)take(128 * 4);
  (void)ws_size; (void)n_in; (void)out_size;

  int egrid = (ET + TPB - 1) / TPB;
  int wgrid = (73728 + TPB - 1) / TPB;
  int fgrid = (ET + N + TPB - 1) / TPB;     // fill + pad-zero threads
  int ngrid = (N + 3) / 4;                  // one node per wave, 4 waves/block
  int mtile = (N + 63) / 64;                // 782
  int mg8 = (mtile + 7) / 8;                // XCD groups for gemm1 swizzle

  // 1 small memset + 3 CSR dispatches
  hipMemsetAsync(deg, 0, zero_bytes, stream);
  k_deg_wprep<<<egrid + wgrid, TPB, 0, stream>>>(ei, E, ET, deg, Wl1, Wr1, Wl2, Wr2,
                                                 wt1l, wt1r, wt2l, wt2r, egrid);
  k_scanf<<<SB, TPB, 0, stream>>>(deg, N, rowoff, cursor);
  k_fill<<<fgrid, TPB, 0, stream>>>(ei, E, ET, N, rowoff, deg, cursor, csrc);

  // Layer 1: GEMM 64-row tiles, XCD-swizzled (4 nt of one m-tile share an XCD)
  k_gemm_mfma<<<mg8 * 32, TPB, 3 * 64 * 128 * 2, stream>>>(
      x, 0, nullptr, wt1l, bl1, wt1r, br1, xl1, xr1, N, 128, 256, mtile, 1);
  k_gat1<<<ngrid, TPB, 0, stream>>>(xl1, xr1, rowoff, deg, csrc, att1, bias1, out1, N);
  k_bnstatfin<<<256, TPB, 0, stream>>>(out1, N, part, ctr, g1, be1, ab1);

  // Layer 2: GEMM reads f16 out1 with fused BN affine + relu
  k_gemm_mfma<<<mtile, TPB, 3 * 64 * 64 * 2, stream>>>(
      out1, 1, ab1, wt2l, bl2, wt2r, br2, xl2, xr2, N, 64, 64, mtile, 0);
  k_gat2<<<ngrid, TPB, 0, stream>>>(xl2, xr2, rowoff, deg, csrc, att2, bias2, out, N);
  // BN2 fused: stats + finalize + spin + apply (replaces 2 dispatches)
  k_bn2fused<<<256, TPB, 0, stream>>>(out, N, part, ctr + 64, ctr + 128, g2, be2, ab2);
}

// Round 18
// 354.248 us; speedup vs baseline: 1.2343x; 1.2343x over previous
//
#include <hip/hip_runtime.h>
#include <hip/hip_bf16.h>
#include <math.h>

#define TPB 256

typedef __attribute__((ext_vector_type(8))) _Float16 hfrag8;
typedef __attribute__((ext_vector_type(2))) _Float16 h2;
typedef __attribute__((ext_vector_type(4))) float f32x4;

union HU { unsigned int u; h2 h; };

static __device__ __forceinline__ h2 as_h2(unsigned int u) { HU c; c.u = u; return c.h; }
static __device__ __forceinline__ unsigned short f2h_bits(float f) {
  union { _Float16 h; unsigned short s; } c; c.h = (_Float16)f; return c.s;
}

// DPP row-rotate ring reduction within each 16-lane row.
#define DPP_ROR(v, C) __int_as_float(__builtin_amdgcn_update_dpp( \
    __float_as_int(v), __float_as_int(v), (C), 0xf, 0xf, false))
static __device__ __forceinline__ float red16(float p) {
  p += DPP_ROR(p, 0x121);  // row_ror:1
  p += DPP_ROR(p, 0x122);  // row_ror:2
  p += DPP_ROR(p, 0x124);  // row_ror:4
  p += DPP_ROR(p, 0x128);  // row_ror:8
  return p;
}

// ---------------- degrees + W->f16 transpose (fused) ----------------
__global__ void k_deg_wprep(const int* __restrict__ ei, int E, int ET, int* __restrict__ deg,
                            const float* __restrict__ Wl1, const float* __restrict__ Wr1,
                            const float* __restrict__ Wl2, const float* __restrict__ Wr2,
                            unsigned short* __restrict__ wt1l, unsigned short* __restrict__ wt1r,
                            unsigned short* __restrict__ wt2l, unsigned short* __restrict__ wt2r,
                            int egrid) {
  int b = blockIdx.x;
  if (b < egrid) {
    int e = b * TPB + threadIdx.x;
    if (e < ET) {
      int dst = (e < E) ? ei[E + e] : (e - E);
      atomicAdd(&deg[dst], 1);
    }
    return;
  }
  int i = (b - egrid) * TPB + threadIdx.x;
  if (i < 32768) {
    int c = i >> 7, k = i & 127;
    wt1l[i] = f2h_bits(Wl1[(size_t)k * 256 + c]);
  } else if (i < 65536) {
    int j = i - 32768; int c = j >> 7, k = j & 127;
    wt1r[j] = f2h_bits(Wr1[(size_t)k * 256 + c]);
  } else if (i < 69632) {
    int j = i - 65536; int c = j >> 6, k = j & 63;
    wt2l[j] = f2h_bits(Wl2[(size_t)k * 64 + c]);
  } else if (i < 73728) {
    int j = i - 69632; int c = j >> 6, k = j & 63;
    wt2r[j] = f2h_bits(Wr2[(size_t)k * 64 + c]);
  }
}

// ---------------- one-dispatch padded-degree scan ----------------
__global__ void k_scanf(const int* __restrict__ deg, int N,
                        int* __restrict__ rowoff, int* __restrict__ cursor) {
  __shared__ int sm[TPB];
  int t = threadIdx.x;
  int pref = blockIdx.x * TPB;
  int acc = 0;
  for (int j = t; j < pref; j += TPB) acc += (deg[j] + 3) & ~3;
  sm[t] = acc;
  __syncthreads();
  for (int d = TPB / 2; d > 0; d >>= 1) {
    if (t < d) sm[t] += sm[t + d];
    __syncthreads();
  }
  int base = sm[0];
  __syncthreads();
  int i = pref + t;
  int v = (i < N) ? ((deg[i] + 3) & ~3) : 0;
  sm[t] = v;
  __syncthreads();
  for (int d = 1; d < TPB; d <<= 1) {
    int tmp = (t >= d) ? sm[t - d] : 0;
    __syncthreads();
    sm[t] += tmp;
    __syncthreads();
  }
  if (i < N) {
    int off = base + sm[t] - v;  // exclusive, 4-aligned
    rowoff[i] = off;
    cursor[i] = off;
  }
}

__global__ void k_fill(const int* __restrict__ ei, int E, int ET,
                       int* __restrict__ cursor, int* __restrict__ csrc) {
  int e = blockIdx.x * blockDim.x + threadIdx.x;
  if (e >= ET) return;
  int src, dst;
  if (e < E) { src = ei[e]; dst = ei[E + e]; } else { src = dst = e - E; }
  int pos = atomicAdd(&cursor[dst], 1);
  csrc[pos] = src;
}

// ---------------- MFMA GEMM: out{0,1}_f16 = act(A_f32) @ Wt{0,1}^T + b{0,1} ----------------
// nt4: XCD-swizzled decode (4 column-tiles of one m-tile -> same XCD, A L2-reuse).
__global__ void k_gemm_mfma(const float* __restrict__ A, const float* __restrict__ affine,
                            const unsigned short* __restrict__ Wt0, const float* __restrict__ b0,
                            const unsigned short* __restrict__ Wt1, const float* __restrict__ b1,
                            unsigned short* __restrict__ out0, unsigned short* __restrict__ out1,
                            int M, int K, int Nc, int mtile, int nt4) {
  extern __shared__ short lds[];
  short* As = lds;
  short* Bls = lds + 64 * K;
  short* Brs = lds + 128 * K;
  int m, nt;
  if (nt4) {
    int xcd = blockIdx.x & 7, gg = blockIdx.x >> 3;
    nt = gg & 3; m = ((gg >> 2) << 3) | xcd;
    if (m >= mtile) return;
  } else {
    m = blockIdx.x; nt = 0;
  }
  const int r0 = m * 64, n0 = nt * 64;
  const int tid = threadIdx.x;
  const int Kb = K * 2;

  // stage A: f32 -> f16 (+optional affine+relu), swizzled
  const int fpr = K >> 2;  // float4 per row
  for (int idx = tid; idx < 64 * fpr; idx += TPB) {
    int row = idx / fpr, c4 = idx - row * fpr;
    int gr = r0 + row;
    float4 v = make_float4(0.f, 0.f, 0.f, 0.f);
    if (gr < M) v = *(const float4*)(A + (size_t)gr * K + c4 * 4);
    if (affine) {
      int c = c4 * 4;
      v.x = fmaxf(v.x * affine[c + 0] + affine[64 + c + 0], 0.f);
      v.y = fmaxf(v.y * affine[c + 1] + affine[64 + c + 1], 0.f);
      v.z = fmaxf(v.z * affine[c + 2] + affine[64 + c + 2], 0.f);
      v.w = fmaxf(v.w * affine[c + 3] + affine[64 + c + 3], 0.f);
    }
    ushort4 pk;
    pk.x = f2h_bits(v.x); pk.y = f2h_bits(v.y); pk.z = f2h_bits(v.z); pk.w = f2h_bits(v.w);
    int kb = (c4 * 8) ^ ((row & 7) << 4);
    *(ushort4*)((char*)As + row * Kb + kb) = pk;
  }
  // stage W0/W1 (already f16, transposed): 16B chunks, swizzled
  const int cpr = K >> 3;
  for (int idx = tid; idx < 64 * cpr; idx += TPB) {
    int c = idx / cpr, k8 = (idx - c * cpr) * 8;
    int kb = (k8 * 2) ^ ((c & 7) << 4);
    uint4 w0 = *(const uint4*)(Wt0 + (size_t)(n0 + c) * K + k8);
    *(uint4*)((char*)Bls + c * Kb + kb) = w0;
    uint4 w1 = *(const uint4*)(Wt1 + (size_t)(n0 + c) * K + k8);
    *(uint4*)((char*)Brs + c * Kb + kb) = w1;
  }
  __syncthreads();

  const int w = tid >> 6, lane = tid & 63;
  const int arow = w * 16 + (lane & 15);
  const int l16 = (lane >> 4) << 3;
  f32x4 accL[4], accR[4];
#pragma unroll
  for (int i = 0; i < 4; ++i) { accL[i] = (f32x4)0.f; accR[i] = (f32x4)0.f; }
  for (int k0 = 0; k0 < K; k0 += 32) {
    int kb = (k0 + l16) * 2;
    hfrag8 af = *(hfrag8*)((char*)As + arow * Kb + (kb ^ ((arow & 7) << 4)));
#pragma unroll
    for (int cf = 0; cf < 4; ++cf) {
      int col = cf * 16 + (lane & 15);
      int cb = col * Kb + (kb ^ ((col & 7) << 4));
      hfrag8 bl = *(hfrag8*)((char*)Bls + cb);
      accL[cf] = __builtin_amdgcn_mfma_f32_16x16x32_f16(af, bl, accL[cf], 0, 0, 0);
      hfrag8 br = *(hfrag8*)((char*)Brs + cb);
      accR[cf] = __builtin_amdgcn_mfma_f32_16x16x32_f16(af, br, accR[cf], 0, 0, 0);
    }
  }
  // epilogue: C/D map col=lane&15, row=(lane>>4)*4+reg
  const int rbase = r0 + w * 16 + ((lane >> 4) << 2);
  const int cbase = n0 + (lane & 15);
#pragma unroll
  for (int cf = 0; cf < 4; ++cf) {
    int gcol = cbase + cf * 16;
    float bb0 = b0[gcol], bb1 = b1[gcol];
#pragma unroll
    for (int r = 0; r < 4; ++r) {
      int grow = rbase + r;
      if (grow < M) {
        out0[(size_t)grow * Nc + gcol] = f2h_bits(accL[cf][r] + bb0);
        out1[(size_t)grow * Nc + gcol] = f2h_bits(accR[cf][r] + bb1);
      }
    }
  }
}

// ---------------- GATv2 layer 1: H=4, C=64; one node/wave; f16 packed math ----------------
__global__ __launch_bounds__(TPB) void k_gat1(
    const unsigned short* __restrict__ xl, const unsigned short* __restrict__ xr,
    const int* __restrict__ rowoff, const int* __restrict__ deg,
    const int* __restrict__ csrc,
    const float* __restrict__ att, const float* __restrict__ bias,
    float* __restrict__ out, int N) {
  int node = (blockIdx.x * TPB + threadIdx.x) >> 6;
  int lane = threadIdx.x & 63;
  if (node >= N) return;
  int l4 = lane * 4;
  float4 atv = *(const float4*)(att + l4);
  h2 at01, at23;
  at01.x = (_Float16)atv.x; at01.y = (_Float16)atv.y;
  at23.x = (_Float16)atv.z; at23.y = (_Float16)atv.w;
  float4 bb = *(const float4*)(bias + l4);
  uint2 rv = *(const uint2*)(xr + (node << 8) + l4);
  h2 xr01 = as_h2(rv.x), xr23 = as_h2(rv.y);
  const _Float16 c02 = (_Float16)0.2f;
  int beg = rowoff[node];
  int dg = deg[node];
  int endR = beg + dg;          // real end
  int endF = beg + (dg & ~3);   // full quads
  float s = 0.f, a0 = 0.f, a1 = 0.f, a2 = 0.f, a3 = 0.f;
  int k = beg;
  for (; k < endF; k += 4) {
    int4 q = *(const int4*)(csrc + k);  // 4-aligned (padded rows)
    uint2 vv[4];
    vv[0] = *(const uint2*)(xl + (q.x << 8) + l4);
    vv[1] = *(const uint2*)(xl + (q.y << 8) + l4);
    vv[2] = *(const uint2*)(xl + (q.z << 8) + l4);
    vv[3] = *(const uint2*)(xl + (q.w << 8) + l4);
    float ps[4];
#pragma unroll
    for (int u = 0; u < 4; ++u) {
      h2 x01 = as_h2(vv[u].x), x23 = as_h2(vv[u].y);
      h2 t01 = x01 + xr01, t23 = x23 + xr23;
      h2 l01 = __builtin_elementwise_max(t01, t01 * c02);
      h2 l23 = __builtin_elementwise_max(t23, t23 * c02);
      ps[u] = __builtin_amdgcn_fdot2(l01, at01,
              __builtin_amdgcn_fdot2(l23, at23, 0.f, false), false);
    }
#pragma unroll
    for (int u = 0; u < 4; ++u) ps[u] = red16(ps[u]);
#pragma unroll
    for (int u = 0; u < 4; ++u) {
      float wv = __expf(ps[u]);
      h2 x01 = as_h2(vv[u].x), x23 = as_h2(vv[u].y);
      s += wv;
      a0 += wv * (float)x01.x; a1 += wv * (float)x01.y;
      a2 += wv * (float)x23.x; a3 += wv * (float)x23.y;
    }
  }
  if (k < endR) {  // one predicated aligned quad (padding srcs are 0 -> valid row)
    int4 q = *(const int4*)(csrc + k);
    uint2 vv[4];
    vv[0] = *(const uint2*)(xl + (q.x << 8) + l4);
    vv[1] = *(const uint2*)(xl + (q.y << 8) + l4);
    vv[2] = *(const uint2*)(xl + (q.z << 8) + l4);
    vv[3] = *(const uint2*)(xl + (q.w << 8) + l4);
    float ps[4];
#pragma unroll
    for (int u = 0; u < 4; ++u) {
      h2 x01 = as_h2(vv[u].x), x23 = as_h2(vv[u].y);
      h2 t01 = x01 + xr01, t23 = x23 + xr23;
      h2 l01 = __builtin_elementwise_max(t01, t01 * c02);
      h2 l23 = __builtin_elementwise_max(t23, t23 * c02);
      ps[u] = __builtin_amdgcn_fdot2(l01, at01,
              __builtin_amdgcn_fdot2(l23, at23, 0.f, false), false);
    }
#pragma unroll
    for (int u = 0; u < 4; ++u) ps[u] = red16(ps[u]);
#pragma unroll
    for (int u = 0; u < 4; ++u) {
      float wv = (k + u < endR) ? __expf(ps[u]) : 0.f;
      h2 x01 = as_h2(vv[u].x), x23 = as_h2(vv[u].y);
      s += wv;
      a0 += wv * (float)x01.x; a1 += wv * (float)x01.y;
      a2 += wv * (float)x23.x; a3 += wv * (float)x23.y;
    }
  }
  float inv = 1.f / (s + 1e-16f);
  a0 *= inv; a1 *= inv; a2 *= inv; a3 *= inv;
  // mean over the 4 heads
  a0 += __shfl_xor(a0, 16); a0 += __shfl_xor(a0, 32);
  a1 += __shfl_xor(a1, 16); a1 += __shfl_xor(a1, 32);
  a2 += __shfl_xor(a2, 16); a2 += __shfl_xor(a2, 32);
  a3 += __shfl_xor(a3, 16); a3 += __shfl_xor(a3, 32);
  if (lane < 16) {
    float4 o;
    o.x = a0 * 0.25f + bb.x;
    o.y = a1 * 0.25f + bb.y;
    o.z = a2 * 0.25f + bb.z;
    o.w = a3 * 0.25f + bb.w;
    *(float4*)(out + (node << 6) + l4) = o;
  }
}

// ---------------- GATv2 layer 2: H=1, C=64; 4 edges/wave; f16 packed math ----------------
__global__ __launch_bounds__(TPB) void k_gat2(
    const unsigned short* __restrict__ xl, const unsigned short* __restrict__ xr,
    const int* __restrict__ rowoff, const int* __restrict__ deg,
    const int* __restrict__ csrc,
    const float* __restrict__ att, const float* __restrict__ bias,
    float* __restrict__ out, int N) {
  int node = (blockIdx.x * TPB + threadIdx.x) >> 6;
  int lane = threadIdx.x & 63;
  if (node >= N) return;
  int grp = lane >> 4, c4 = (lane & 15) * 4;
  float4 atv = *(const float4*)(att + c4);
  h2 at01, at23;
  at01.x = (_Float16)atv.x; at01.y = (_Float16)atv.y;
  at23.x = (_Float16)atv.z; at23.y = (_Float16)atv.w;
  float4 bb = *(const float4*)(bias + c4);
  uint2 rv = *(const uint2*)(xr + (node << 6) + c4);
  h2 xr01 = as_h2(rv.x), xr23 = as_h2(rv.y);
  const _Float16 c02 = (_Float16)0.2f;
  int beg = rowoff[node];
  int dg = deg[node];
  int endR = beg + dg;
  int quads = (dg + 3) >> 2;  // padded rows -> safe aligned reads
  float s = 0.f, a0 = 0.f, a1 = 0.f, a2 = 0.f, a3 = 0.f;
  for (int it = 0; it < quads; ++it) {
    int kk = beg + it * 4 + grp;
    int src = csrc[kk];                 // padding reads src=0 (valid row)
    bool ok = kk < endR;
    uint2 v = *(const uint2*)(xl + (src << 6) + c4);
    h2 x01 = as_h2(v.x), x23 = as_h2(v.y);
    h2 t01 = x01 + xr01, t23 = x23 + xr23;
    h2 l01 = __builtin_elementwise_max(t01, t01 * c02);
    h2 l23 = __builtin_elementwise_max(t23, t23 * c02);
    float p = __builtin_amdgcn_fdot2(l01, at01,
              __builtin_amdgcn_fdot2(l23, at23, 0.f, false), false);
    p = red16(p);
    float wv = ok ? __expf(p) : 0.f;
    s += wv;
    a0 += wv * (float)x01.x; a1 += wv * (float)x01.y;
    a2 += wv * (float)x23.x; a3 += wv * (float)x23.y;
  }
  // sum the 4 edge-groups
  s += __shfl_xor(s, 16); s += __shfl_xor(s, 32);
  a0 += __shfl_xor(a0, 16); a0 += __shfl_xor(a0, 32);
  a1 += __shfl_xor(a1, 16); a1 += __shfl_xor(a1, 32);
  a2 += __shfl_xor(a2, 16); a2 += __shfl_xor(a2, 32);
  a3 += __shfl_xor(a3, 16); a3 += __shfl_xor(a3, 32);
  if (lane < 16) {
    float inv = 1.f / (s + 1e-16f);
    float4 o;
    o.x = a0 * inv + bb.x;
    o.y = a1 * inv + bb.y;
    o.z = a2 * inv + bb.z;
    o.w = a3 * inv + bb.w;
    *(float4*)(out + (node << 6) + c4) = o;
  }
}

// ---------------- BatchNorm stats + last-block PARALLEL finalize ----------------
__global__ void k_bnstatfin(const float* __restrict__ in, int N, float* __restrict__ part,
                            int* __restrict__ counter, const float* __restrict__ g,
                            const float* __restrict__ beta, float* __restrict__ ab) {
  __shared__ float sm[TPB], sq[TPB];
  __shared__ float fin[TPB];
  __shared__ int lastsm;
  int col = threadIdx.x & 63;
  int rq = threadIdx.x >> 6;
  float s0 = 0.f, q0 = 0.f, s1 = 0.f, q1 = 0.f;
  int stride = gridDim.x * 4;
  int r = blockIdx.x * 4 + rq;
  for (; r + stride < N; r += 2 * stride) {
    float v0 = in[(size_t)r * 64 + col];
    float v1 = in[(size_t)(r + stride) * 64 + col];
    s0 += v0; q0 += v0 * v0;
    s1 += v1; q1 += v1 * v1;
  }
  if (r < N) {
    float v0 = in[(size_t)r * 64 + col];
    s0 += v0; q0 += v0 * v0;
  }
  sm[threadIdx.x] = s0 + s1; sq[threadIdx.x] = q0 + q1;
  __syncthreads();
  if (threadIdx.x < 128) {
    float v;
    if (threadIdx.x < 64) {
      v = sm[threadIdx.x] + sm[threadIdx.x + 64] + sm[threadIdx.x + 128] + sm[threadIdx.x + 192];
    } else {
      int c = threadIdx.x - 64;
      v = sq[c] + sq[c + 64] + sq[c + 128] + sq[c + 192];
    }
    part[(size_t)blockIdx.x * 128 + threadIdx.x] = v;
  }
  __threadfence();
  __syncthreads();
  if (threadIdx.x == 0) lastsm = atomicAdd(counter, 1);
  __syncthreads();
  if (lastsm != gridDim.x - 1) return;
  __threadfence();
  int t = threadIdx.x;
  int c = t & 127, gidx = t >> 7;
  int B = gridDim.x;
  float acc0 = 0.f, acc1 = 0.f, acc2 = 0.f, acc3 = 0.f;
  int b = gidx;
  for (; b + 6 < B; b += 8) {
    acc0 += part[(size_t)b * 128 + c];
    acc1 += part[(size_t)(b + 2) * 128 + c];
    acc2 += part[(size_t)(b + 4) * 128 + c];
    acc3 += part[(size_t)(b + 6) * 128 + c];
  }
  for (; b < B; b += 2) acc0 += part[(size_t)b * 128 + c];
  fin[t] = (acc0 + acc1) + (acc2 + acc3);
  __syncthreads();
  if (t < 64) {
    float ts = fin[t] + fin[t + 128];
    float tq = fin[t + 64] + fin[t + 192];
    float mean = ts / (float)N;
    float var = tq / (float)N - mean * mean;
    float a = g[t] * rsqrtf(var + 1e-5f);
    ab[t] = a;
    ab[64 + t] = beta[t] - mean * a;
  }
}

__global__ void k_bnapply(const float* __restrict__ in, const float* __restrict__ ab,
                          float* __restrict__ out, int total4) {
  int idx = blockIdx.x * blockDim.x + threadIdx.x;
  if (idx >= total4) return;
  float4 v = *(const float4*)(in + (size_t)idx * 4);
  int c0 = (idx & 15) * 4;
  v.x = fmaxf(v.x * ab[c0 + 0] + ab[64 + c0 + 0], 0.f);
  v.y = fmaxf(v.y * ab[c0 + 1] + ab[64 + c0 + 1], 0.f);
  v.z = fmaxf(v.z * ab[c0 + 2] + ab[64 + c0 + 2], 0.f);
  v.w = fmaxf(v.w * ab[c0 + 3] + ab[64 + c0 + 3], 0.f);
  *(float4*)(out + (size_t)idx * 4) = v;
}

extern "C" void kernel_launch(void* const* d_in, const int* in_sizes, int n_in,
                              void* d_out, int out_size, void* d_ws, size_t ws_size,
                              hipStream_t stream) {
  const float* x     = (const float*)d_in[0];
  const int*   ei    = (const int*)d_in[1];
  const float* Wl1   = (const float*)d_in[2];
  const float* bl1   = (const float*)d_in[3];
  const float* Wr1   = (const float*)d_in[4];
  const float* br1   = (const float*)d_in[5];
  const float* att1  = (const float*)d_in[6];
  const float* bias1 = (const float*)d_in[7];
  const float* g1    = (const float*)d_in[8];
  const float* be1   = (const float*)d_in[9];
  const float* Wl2   = (const float*)d_in[10];
  const float* bl2   = (const float*)d_in[11];
  const float* Wr2   = (const float*)d_in[12];
  const float* br2   = (const float*)d_in[13];
  const float* att2  = (const float*)d_in[14];
  const float* bias2 = (const float*)d_in[15];
  const float* g2    = (const float*)d_in[16];
  const float* be2   = (const float*)d_in[17];
  float* out = (float*)d_out;

  const int N  = in_sizes[0] / 128;   // 50000
  const int E  = in_sizes[1] / 2;     // 800000
  const int ET = E + N;
  const int ETP = ET + 4 * ((N + 255) & ~255);  // padded-CSR upper bound
  const int SB = (N + TPB - 1) / TPB; // 196

  char* p = (char*)d_ws;
  auto take = [&](size_t b) { char* q = p; p += (b + 255) & ~(size_t)255; return q; };

  unsigned short* xl1 = (unsigned short*)take((size_t)N * 256 * 2);
  unsigned short* xr1 = (unsigned short*)take((size_t)N * 256 * 2);
  unsigned short* xl2 = (unsigned short*)take((size_t)N * 64 * 2);
  unsigned short* xr2 = (unsigned short*)take((size_t)N * 64 * 2);
  float* out1 = (float*)take((size_t)N * 64 * 4);
  unsigned short* wt1l = (unsigned short*)take(256 * 128 * 2);
  unsigned short* wt1r = (unsigned short*)take(256 * 128 * 2);
  unsigned short* wt2l = (unsigned short*)take(64 * 64 * 2);
  unsigned short* wt2r = (unsigned short*)take(64 * 64 * 2);
  // zeroed span: deg + counters + csrc (padding zeros)
  int* deg    = (int*)take((size_t)N * 4);
  int* ctr    = (int*)take(512);          // counters at ctr[0], ctr[64]
  int* csrc   = (int*)take((size_t)ETP * 4 + 16);
  size_t zero_bytes = (char*)(csrc + ETP) + 16 - (char*)deg;
  int* rowoff = (int*)take((size_t)(N + 1) * 4);
  int* cursor = (int*)take((size_t)N * 4);
  float* part = (float*)take((size_t)256 * 128 * 4);
  float* ab1  = (float*)take(128 * 4);
  float* ab2  = (float*)take(128 * 4);
  (void)ws_size; (void)n_in; (void)out_size;

  int egrid = (ET + TPB - 1) / TPB;
  int wgrid = (73728 + TPB - 1) / TPB;
  int ngrid = (N + 3) / 4;              // one node per wave, 4 waves/block
  int mtile = (N + 63) / 64;            // 782
  int mg8 = (mtile + 7) / 8;            // XCD groups for gemm1 swizzle
  int total4 = N * 16;

  // 1 memset + 3 CSR dispatches
  hipMemsetAsync(deg, 0, zero_bytes, stream);
  k_deg_wprep<<<egrid + wgrid, TPB, 0, stream>>>(ei, E, ET, deg, Wl1, Wr1, Wl2, Wr2,
                                                 wt1l, wt1r, wt2l, wt2r, egrid);
  k_scanf<<<SB, TPB, 0, stream>>>(deg, N, rowoff, cursor);
  k_fill<<<egrid, TPB, 0, stream>>>(ei, E, ET, cursor, csrc);

  // Layer 1: GEMM (XCD-swizzled: 4 column-tiles of one m-tile share an XCD)
  k_gemm_mfma<<<mg8 * 32, TPB, 3 * 64 * 128 * 2, stream>>>(
      x, nullptr, wt1l, bl1, wt1r, br1, xl1, xr1, N, 128, 256, mtile, 1);
  k_gat1<<<ngrid, TPB, 0, stream>>>(xl1, xr1, rowoff, deg, csrc, att1, bias1, out1, N);
  k_bnstatfin<<<256, TPB, 0, stream>>>(out1, N, part, ctr, g1, be1, ab1);

  // Layer 2: BN affine + relu fused into GEMM A-staging
  k_gemm_mfma<<<mtile, TPB, 3 * 64 * 64 * 2, stream>>>(
      out1, ab1, wt2l, bl2, wt2r, br2, xl2, xr2, N, 64, 64, mtile, 0);
  k_gat2<<<ngrid, TPB, 0, stream>>>(xl2, xr2, rowoff, deg, csrc, att2, bias2, out, N);
  k_bnstatfin<<<256, TPB, 0, stream>>>(out, N, part, ctr + 64, g2, be2, ab2);
  k_bnapply<<<(total4 + TPB - 1) / TPB, TPB, 0, stream>>>(out, ab2, out, total4);
}